// Round 15
// baseline (1505.909 us; speedup 1.0000x reference)
//
#include <hip/hip_runtime.h>
#include <hip/hip_bf16.h>
#include <math.h>

#define B 4
#define S 2048
#define H 768
#define V 32000
#define HID 100
#define G4 400   // 4*HID
#define M_TOT (B*S)
#define PD 2     // xproj prefetch depth (steps)

typedef _Float16 half2_t __attribute__((ext_vector_type(2)));
typedef _Float16 half8_t __attribute__((ext_vector_type(8)));

__device__ __forceinline__ float fdot2_(half2_t a, half2_t b, float c) {
#if __has_builtin(__builtin_amdgcn_fdot2)
  return __builtin_amdgcn_fdot2(a, b, c, false);
#else
  return c + (float)a[0] * (float)b[0] + (float)a[1] * (float)b[1];
#endif
}

__device__ __forceinline__ float sigmoidf_(float x) {
  return 1.0f / (1.0f + __expf(-x));
}

// Raw workgroup barrier: orders LDS (lgkmcnt drain) without forcing the
// compiler's full vmcnt(0)+expcnt drain of __syncthreads.
__device__ __forceinline__ void lds_barrier_() {
  asm volatile("s_waitcnt lgkmcnt(0)" ::: "memory");
  __builtin_amdgcn_s_barrier();
  asm volatile("" ::: "memory");
}

// ---------------- Kernel 1: FUSED surprisal + x_proj GEMM (INTERLEAVED) ------
// 9088 blocks = 128 groups of 71: in each group, blocks 0..6 are GEMM tiles
// (7*128 = 896) and blocks 7..70 are surprisal rows (64*128 = 8192). The
// uniform interleave keeps every CU holding a MIX of HBM-bound surprisal and
// VALU-bound GEMM at all times, so the GEMM compute hides inside surprisal's
// memory time (r14 put all GEMM blocks first -> they filled the CUs and the
// phases serialized anyway).
// GEMM writes PERMUTED col 4*unit + bitrev2(gate), biases folded, NO surp
// term (the rank-1 surp correction is folded into the LSTM kernel).
#define BM 64
#define BN 64
#define BK 32
#define NTM (M_TOT / BM)          // 128
#define NTN ((G4 + BN - 1) / BN)  // 7
#define NGEMM (NTM * NTN)         // 896
#define GRP 71                    // 7 GEMM + 64 surprisal per group

__global__ __launch_bounds__(256) void fused_pre_kernel(
    const float* __restrict__ logits, const int* __restrict__ ids,
    const float* __restrict__ mask, float* __restrict__ surp,
    const float* __restrict__ A,     // hidden_states [M,768]
    const float* __restrict__ W,     // W_ih [400,769]
    const float* __restrict__ b_ih, const float* __restrict__ b_hh,
    float* __restrict__ xproj) {     // [M,400] permuted
  __shared__ float smem[BK * BM + BK * BN];   // 16 KB, shared by both paths
  int tid = threadIdx.x;
  int grp = blockIdx.x / GRP;
  int sub = blockIdx.x % GRP;

  if (sub < NTN) {
    // ---------------- GEMM part ----------------
    float (*As)[BM] = (float(*)[BM])smem;
    float (*Bs)[BN] = (float(*)[BN])(smem + BK * BM);
    int m0 = grp * BM;          // grp in 0..127 = M tile
    int n0 = sub * BN;          // sub in 0..6   = N tile
    int tx = tid & 15, ty = tid >> 4;
    float acc[4][4] = {};
    for (int k0 = 0; k0 < H; k0 += BK) {
      #pragma unroll
      for (int l = 0; l < 2; ++l) {
        int idx = tid + l * 256;        // 0..511
        int row = idx >> 3;
        int kq = idx & 7;
        float4 v = *(const float4*)&A[(size_t)(m0 + row) * H + k0 + kq * 4];
        As[kq * 4 + 0][row] = v.x;
        As[kq * 4 + 1][row] = v.y;
        As[kq * 4 + 2][row] = v.z;
        As[kq * 4 + 3][row] = v.w;
      }
      #pragma unroll
      for (int l = 0; l < 8; ++l) {
        int idx = tid + l * 256;        // 0..2047
        int n = idx >> 5;
        int kk = idx & 31;
        int gn = n0 + n;
        Bs[kk][n] = (gn < G4) ? W[(size_t)gn * (H + 1) + k0 + kk] : 0.0f;
      }
      __syncthreads();
      #pragma unroll
      for (int k = 0; k < BK; ++k) {
        float4 a = *(const float4*)&As[k][ty * 4];
        float4 bq = *(const float4*)&Bs[k][tx * 4];
        float av[4] = {a.x, a.y, a.z, a.w};
        float bv[4] = {bq.x, bq.y, bq.z, bq.w};
        #pragma unroll
        for (int i = 0; i < 4; ++i)
          #pragma unroll
          for (int j = 0; j < 4; ++j)
            acc[i][j] += av[i] * bv[j];
      }
      __syncthreads();
    }
    #pragma unroll
    for (int i = 0; i < 4; ++i) {
      int gm = m0 + ty * 4 + i;
      #pragma unroll
      for (int j = 0; j < 4; ++j) {
        int gn = n0 + tx * 4 + j;   // gate-row index r = g*100 + k
        if (gn < G4) {
          float val = acc[i][j] + b_ih[gn] + b_hh[gn];
          int g = gn / HID, k = gn % HID;
          int pn = 4 * k + (((g & 1) << 1) | (g >> 1));   // bitrev2(g)
          xproj[(size_t)gm * G4 + pn] = val;
        }
      }
    }
  } else {
    // ---------------- surprisal part ----------------
    int row = grp * 64 + (sub - NTN);   // 0..8191
    const float* x = logits + (size_t)row * V;
    float m = -INFINITY, s = 0.0f;
    const float4* x4 = (const float4*)x;
    for (int i = tid; i < V / 4; i += 256) {
      float4 v = x4[i];
      float mv = fmaxf(fmaxf(v.x, v.y), fmaxf(v.z, v.w));
      if (mv > m) { s *= __expf(m - mv); m = mv; }
      s += __expf(v.x - m) + __expf(v.y - m) + __expf(v.z - m) + __expf(v.w - m);
    }
    #pragma unroll
    for (int off = 32; off > 0; off >>= 1) {
      float mo = __shfl_xor(m, off);
      float so = __shfl_xor(s, off);
      float mn = fmaxf(m, mo);
      s = s * __expf(m - mn) + so * __expf(mo - mn);
      m = mn;
    }
    float* sm = smem;        // reuse GEMM LDS
    float* ss = smem + 4;
    int wid = tid >> 6, lane = tid & 63;
    if (lane == 0) { sm[wid] = m; ss[wid] = s; }
    __syncthreads();
    if (tid == 0) {
      float M = sm[0], Ssum = ss[0];
      #pragma unroll
      for (int w = 1; w < 4; ++w) {
        float mo = sm[w], so = ss[w];
        float mn = fmaxf(M, mo);
        Ssum = Ssum * __expf(M - mn) + so * __expf(mo - mn);
        M = mn;
      }
      float xid = x[ids[row]];
      surp[row] = (M + __logf(Ssum) - xid) * 1.4426950408889634f * mask[row];
    }
  }
}

// ---------------- Kernel 2: LSTM scan + classifier (round-8 + surp fold) -----
// Thread q (q<200) owns TWO gate rows of unit k=q/2: even q -> (i,g) rows;
// odd q -> (f,o). Weights half2 in regs; 13 uniform ds_read_b128 h-broadcast;
// 104 v_dot2_f32_f16; local activations; two shfl_xor(1); c update; even lane
// writes h[k] (f16). One raw barrier/step; double-buffered h; PD=2 coalesced
// float2 xproj ring. NEW: the rank-1 surprisal term (surp[t] * W_ih[:,768])
// is folded here — wl pair preloaded, surp_t rides the prefetch ring; +2 FMA
// per step (replaces the separate rank1 RMW kernel + launch).
#define NH2 52          // 50 half2 + 2 zero-pad -> 13 x b128
__global__ __launch_bounds__(256, 1) void lstm_kernel(
    const float* __restrict__ xproj,  // [B,S,400] permuted cols
    const float* __restrict__ surp,   // [B*S]
    const float* __restrict__ W_ih,   // [400,769] (last col = surp weight)
    const float* __restrict__ W_hh,   // [400,100]
    const float* __restrict__ sent,   // [B,3]
    const float* __restrict__ cls_W,  // [3,103]
    const float* __restrict__ cls_b,  // [3]
    float* __restrict__ out) {        // [B,3]
  int b = blockIdx.x;
  int tid = threadIdx.x;
  __shared__ __align__(16) _Float16 hb0[2 * NH2];
  __shared__ __align__(16) _Float16 hb1[2 * NH2];

  bool active = tid < 200;
  int q = active ? tid : 199;          // clamp for uniform control flow
  int k = q >> 1;
  bool odd = (q & 1) != 0;
  int rA = odd ? (HID + k) : k;                  // f : i
  int rB = odd ? (3 * HID + k) : (2 * HID + k);  // o : g

  half2_t wA[NH2], wB[NH2];
  float wlA, wlB;                      // surp (last-column) weights
  {
    const float* pA = W_hh + (size_t)rA * HID;
    const float* pB = W_hh + (size_t)rB * HID;
    #pragma unroll
    for (int j = 0; j < 50; ++j) {
      wA[j] = half2_t{(_Float16)pA[2 * j], (_Float16)pA[2 * j + 1]};
      wB[j] = half2_t{(_Float16)pB[2 * j], (_Float16)pB[2 * j + 1]};
    }
    #pragma unroll
    for (int j = 50; j < NH2; ++j) { wA[j] = half2_t{0, 0}; wB[j] = half2_t{0, 0}; }
    wlA = W_ih[(size_t)rA * (H + 1) + H];
    wlB = W_ih[(size_t)rB * (H + 1) + H];
  }

  float c_reg = 0.0f;
  if (tid < 2 * NH2) { hb0[tid] = (_Float16)0; hb1[tid] = (_Float16)0; }
  __syncthreads();

  const float* xp = xproj + (size_t)b * S * G4;
  const float* sp = surp + (size_t)b * S;
  float2 xr[PD];
  float sr[PD];
  #pragma unroll
  for (int d = 0; d < PD; ++d) {
    xr[d] = ((const float2*)(xp + (size_t)d * G4))[q];
    sr[d] = sp[d];
  }

  #pragma unroll 2
  for (int t = 0; t < S; ++t) {
    int slot = t & (PD - 1);                       // static under unroll 2
    const half8_t* hr = (t & 1) ? (const half8_t*)hb0 : (const half8_t*)hb1;
    _Float16* hw = (t & 1) ? hb1 : hb0;

    float2 xv = xr[slot];
    float sv = sr[slot];
    // refill ring slot early (independent; stays in flight across barriers)
    {
      int tp = (t + PD < S) ? (t + PD) : (S - 1);
      xr[slot] = ((const float2*)(xp + (size_t)tp * G4))[q];
      sr[slot] = sp[tp];
    }

    float a0 = 0.f, a1 = 0.f, b0 = 0.f, b1 = 0.f;
    #pragma unroll
    for (int j = 0; j < 13; ++j) {
      half8_t hv = hr[j];                          // uniform addr -> broadcast
      half2_t h0 = {hv[0], hv[1]}, h1 = {hv[2], hv[3]};
      half2_t h2 = {hv[4], hv[5]}, h3 = {hv[6], hv[7]};
      a0 = fdot2_(wA[4 * j + 0], h0, a0);
      b0 = fdot2_(wB[4 * j + 0], h0, b0);
      a1 = fdot2_(wA[4 * j + 1], h1, a1);
      b1 = fdot2_(wB[4 * j + 1], h1, b1);
      a0 = fdot2_(wA[4 * j + 2], h2, a0);
      b0 = fdot2_(wB[4 * j + 2], h2, b0);
      a1 = fdot2_(wA[4 * j + 3], h3, a1);
      b1 = fdot2_(wB[4 * j + 3], h3, b1);
    }
    float aA = a0 + a1 + xv.x + sv * wlA;   // even: i_pre ; odd: f_pre
    float aB = b0 + b1 + xv.y + sv * wlB;   // even: g_pre ; odd: o_pre

    // local activations (uniform instruction stream, per-lane selects):
    float vA = sigmoidf_(aA);                       // i or f
    float sB = sigmoidf_(odd ? aB : 2.0f * aB);
    float vB = odd ? sB : (2.0f * sB - 1.0f);       // o or tanh(g)

    // two independent pair-exchanges: even lane receives f and o
    float f_n = __shfl_xor(vA, 1);
    float o_n = __shfl_xor(vB, 1);

    // cell update on even lanes: c = f*c + i*g ; h = o * tanh(c)
    c_reg = f_n * c_reg + vA * vB;
    float tc = 2.0f * sigmoidf_(2.0f * c_reg) - 1.0f;
    float h = o_n * tc;
    if (active && !odd) hw[k] = (_Float16)h;

    lds_barrier_();   // h_t visible; next step writes the OTHER buffer
  }

  // S even -> final h (t = S-1, odd) is in hb1
  if (tid < 3) {
    float acc = cls_b[tid];
    const float* cw = cls_W + tid * (HID + 3);
    #pragma unroll
    for (int j = 0; j < HID; ++j) acc += cw[j] * (float)hb1[j];
    #pragma unroll
    for (int k2 = 0; k2 < 3; ++k2) acc += cw[HID + k2] * sent[b * 3 + k2];
    out[b * 3 + tid] = acc;
  }
}

extern "C" void kernel_launch(void* const* d_in, const int* in_sizes, int n_in,
                              void* d_out, int out_size, void* d_ws, size_t ws_size,
                              hipStream_t stream) {
  const int*   input_ids = (const int*)d_in[0];
  const float* mask      = (const float*)d_in[1];
  const float* sent      = (const float*)d_in[2];
  const float* hs        = (const float*)d_in[3];
  const float* logits    = (const float*)d_in[4];
  const float* W_ih      = (const float*)d_in[5];
  const float* W_hh      = (const float*)d_in[6];
  const float* b_ih      = (const float*)d_in[7];
  const float* b_hh      = (const float*)d_in[8];
  const float* cls_W     = (const float*)d_in[9];
  const float* cls_b     = (const float*)d_in[10];
  float* out = (float*)d_out;

  float* surp  = (float*)d_ws;            // M_TOT floats
  float* xproj = surp + M_TOT;            // M_TOT*400 floats

  fused_pre_kernel<<<GRP * 128, 256, 0, stream>>>(
      logits, input_ids, mask, surp, hs, W_ih, b_ih, b_hh, xproj);
  lstm_kernel<<<B, 256, 0, stream>>>(xproj, surp, W_ih, W_hh, sent, cls_W,
                                     cls_b, out);
}

// Round 16
// 1505.516 us; speedup vs baseline: 1.0003x; 1.0003x over previous
//
#include <hip/hip_runtime.h>
#include <hip/hip_bf16.h>
#include <math.h>

#define B 4
#define S 2048
#define H 768
#define V 32000
#define HID 100
#define G4 400   // 4*HID
#define M_TOT (B*S)
#define PD 2     // xproj prefetch depth (steps)

#define BM 64
#define BN 64
#define BK 32
#define NTM (M_TOT / BM)          // 128 m-tiles
#define NTN ((G4 + BN - 1) / BN)  // 7 n-tiles
#define NGEMM (NTM * NTN)         // 896
#define NLSTM B                   // 4
#define GEMM_BASE NLSTM           // 4
#define SURP_BASE (NLSTM + NGEMM) // 900
#define NBLK (SURP_BASE + M_TOT)  // 9092
#define TARGET (NTN + BM)         // 71 signals per m-tile (7 GEMM + 64 surp)
#define NH2 52                    // 50 half2 + 2 zero-pad -> 13 x b128

typedef _Float16 half2_t __attribute__((ext_vector_type(2)));
typedef _Float16 half8_t __attribute__((ext_vector_type(8)));
typedef float f4v __attribute__((ext_vector_type(4)));

__device__ __forceinline__ float fdot2_(half2_t a, half2_t b, float c) {
#if __has_builtin(__builtin_amdgcn_fdot2)
  return __builtin_amdgcn_fdot2(a, b, c, false);
#else
  return c + (float)a[0] * (float)b[0] + (float)a[1] * (float)b[1];
#endif
}

__device__ __forceinline__ float sigmoidf_(float x) {
  return 1.0f / (1.0f + __expf(-x));
}

// Raw workgroup barrier: orders LDS without the full vmcnt drain.
__device__ __forceinline__ void lds_barrier_() {
  asm volatile("s_waitcnt lgkmcnt(0)" ::: "memory");
  __builtin_amdgcn_s_barrier();
  asm volatile("" ::: "memory");
}

__device__ __forceinline__ void wait_tile_(int* cnt, int idx) {
  while (__hip_atomic_load(&cnt[idx], __ATOMIC_ACQUIRE,
                           __HIP_MEMORY_SCOPE_AGENT) < TARGET)
    __builtin_amdgcn_s_sleep(2);
}

// ---------------- MEGA KERNEL: block roles + flow control --------------------
// blocks [0,4):        LSTM, one per batch; spins per 64-step chunk on cnt[].
// blocks [4,900):      xproj GEMM tiles (bias folded, permuted bitrev2 cols,
//                      NO surp term). Signal cnt[m-tile] after stores.
// blocks [900,9092):   surprisal rows, t-major order (row=(j&3)*S + (j>>2))
//                      so early chunks of all batches finish first; logits
//                      read non-temporally. Signal cnt[row/64].
// Only the 4 LSTM blocks ever wait -> deadlock-free under any dispatch order.
__global__ __launch_bounds__(256, 1) void mega_kernel(
    const float* __restrict__ logits, const int* __restrict__ ids,
    const float* __restrict__ mask,
    const float* __restrict__ hs,     // [M,768]
    const float* __restrict__ W_ih,   // [400,769]
    const float* __restrict__ W_hh,   // [400,100]
    const float* __restrict__ b_ih, const float* __restrict__ b_hh,
    const float* __restrict__ sent, const float* __restrict__ cls_W,
    const float* __restrict__ cls_b,
    float* __restrict__ surp, float* __restrict__ xproj,
    int* cnt, float* __restrict__ out) {
  __shared__ __align__(16) float smem[BK * BM + BK * BN];   // 16 KB
  int tid = threadIdx.x;
  int bid = blockIdx.x;

  if (bid >= SURP_BASE) {
    // ======================= surprisal =======================
    int j = bid - SURP_BASE;
    int row = (j & 3) * S + (j >> 2);          // t-major across batches
    const float* x = logits + (size_t)row * V;
    float m = -INFINITY, s = 0.0f;
    const f4v* x4 = (const f4v*)x;
    for (int i = tid; i < V / 4; i += 256) {
      f4v v = __builtin_nontemporal_load(x4 + i);
      float mv = fmaxf(fmaxf(v[0], v[1]), fmaxf(v[2], v[3]));
      if (mv > m) { s *= __expf(m - mv); m = mv; }
      s += __expf(v[0] - m) + __expf(v[1] - m) + __expf(v[2] - m) + __expf(v[3] - m);
    }
    #pragma unroll
    for (int off = 32; off > 0; off >>= 1) {
      float mo = __shfl_xor(m, off);
      float so = __shfl_xor(s, off);
      float mn = fmaxf(m, mo);
      s = s * __expf(m - mn) + so * __expf(mo - mn);
      m = mn;
    }
    float* sm = smem;
    float* ss = smem + 4;
    int wid = tid >> 6, lane = tid & 63;
    if (lane == 0) { sm[wid] = m; ss[wid] = s; }
    __syncthreads();
    if (tid == 0) {
      float M = sm[0], Ssum = ss[0];
      #pragma unroll
      for (int w = 1; w < 4; ++w) {
        float mo = sm[w], so = ss[w];
        float mn = fmaxf(M, mo);
        Ssum = Ssum * __expf(M - mn) + so * __expf(mo - mn);
        M = mn;
      }
      float xid = x[ids[row]];
      surp[row] = (M + __logf(Ssum) - xid) * 1.4426950408889634f * mask[row];
      __hip_atomic_fetch_add(&cnt[row >> 6], 1, __ATOMIC_RELEASE,
                             __HIP_MEMORY_SCOPE_AGENT);
    }
  } else if (bid >= GEMM_BASE) {
    // ======================= xproj GEMM =======================
    float (*As)[BM] = (float(*)[BM])smem;
    float (*Bs)[BN] = (float(*)[BN])(smem + BK * BM);
    int g = bid - GEMM_BASE;
    int m0 = (g / NTN) * BM;
    int n0 = (g % NTN) * BN;
    int tx = tid & 15, ty = tid >> 4;
    float acc[4][4] = {};
    for (int k0 = 0; k0 < H; k0 += BK) {
      #pragma unroll
      for (int l = 0; l < 2; ++l) {
        int idx = tid + l * 256;
        int row = idx >> 3;
        int kq = idx & 7;
        float4 v = *(const float4*)&hs[(size_t)(m0 + row) * H + k0 + kq * 4];
        As[kq * 4 + 0][row] = v.x;
        As[kq * 4 + 1][row] = v.y;
        As[kq * 4 + 2][row] = v.z;
        As[kq * 4 + 3][row] = v.w;
      }
      #pragma unroll
      for (int l = 0; l < 8; ++l) {
        int idx = tid + l * 256;
        int n = idx >> 5;
        int kk = idx & 31;
        int gn = n0 + n;
        Bs[kk][n] = (gn < G4) ? W_ih[(size_t)gn * (H + 1) + k0 + kk] : 0.0f;
      }
      __syncthreads();
      #pragma unroll
      for (int k = 0; k < BK; ++k) {
        float4 a = *(const float4*)&As[k][ty * 4];
        float4 bq = *(const float4*)&Bs[k][tx * 4];
        float av[4] = {a.x, a.y, a.z, a.w};
        float bv[4] = {bq.x, bq.y, bq.z, bq.w};
        #pragma unroll
        for (int i = 0; i < 4; ++i)
          #pragma unroll
          for (int j = 0; j < 4; ++j)
            acc[i][j] += av[i] * bv[j];
      }
      __syncthreads();
    }
    #pragma unroll
    for (int i = 0; i < 4; ++i) {
      int gm = m0 + ty * 4 + i;
      #pragma unroll
      for (int j = 0; j < 4; ++j) {
        int gn = n0 + tx * 4 + j;
        if (gn < G4) {
          float val = acc[i][j] + b_ih[gn] + b_hh[gn];
          int gg = gn / HID, kk = gn % HID;
          int pn = 4 * kk + (((gg & 1) << 1) | (gg >> 1));   // bitrev2(g)
          xproj[(size_t)gm * G4 + pn] = val;
        }
      }
    }
    __syncthreads();   // all stores issued (vmcnt drained per wave)
    if (tid == 0)
      __hip_atomic_fetch_add(&cnt[m0 >> 6], 1, __ATOMIC_RELEASE,
                             __HIP_MEMORY_SCOPE_AGENT);
  } else {
    // ======================= LSTM (round-8 core + surp fold) =================
    int b = bid;
    _Float16* hb0 = (_Float16*)smem;           // 104 halves @ byte 0
    _Float16* hb1 = ((_Float16*)smem) + 128;   // 104 halves @ byte 256

    bool active = tid < 200;
    int q = active ? tid : 199;
    int k = q >> 1;
    bool odd = (q & 1) != 0;
    int rA = odd ? (HID + k) : k;                  // f : i
    int rB = odd ? (3 * HID + k) : (2 * HID + k);  // o : g

    half2_t wA[NH2], wB[NH2];
    float wlA, wlB;
    {
      const float* pA = W_hh + (size_t)rA * HID;
      const float* pB = W_hh + (size_t)rB * HID;
      #pragma unroll
      for (int j = 0; j < 50; ++j) {
        wA[j] = half2_t{(_Float16)pA[2 * j], (_Float16)pA[2 * j + 1]};
        wB[j] = half2_t{(_Float16)pB[2 * j], (_Float16)pB[2 * j + 1]};
      }
      #pragma unroll
      for (int j = 50; j < NH2; ++j) { wA[j] = half2_t{0, 0}; wB[j] = half2_t{0, 0}; }
      wlA = W_ih[(size_t)rA * (H + 1) + H];
      wlB = W_ih[(size_t)rB * (H + 1) + H];
    }

    float c_reg = 0.0f;
    if (tid < 104) { hb0[tid] = (_Float16)0; hb1[tid] = (_Float16)0; }
    __syncthreads();

    const float* xp = xproj + (size_t)b * S * G4;
    const float* sp = surp + (size_t)b * S;
    int tile0 = b * 32;

    wait_tile_(cnt, tile0);          // chunk 0 ready (xproj rows 0..63 + surp)

    float2 xr[PD];
    #pragma unroll
    for (int d = 0; d < PD; ++d)
      xr[d] = ((const float2*)(xp + (size_t)d * G4))[q];
    float4 sv_cur = *(const float4*)sp;   // surp[0..3]
    float4 sv_nxt = sv_cur;

    #pragma unroll 4
    for (int t = 0; t < S; ++t) {
      if ((t & 63) == 0) {           // chunk boundary: ensure NEXT chunk ready
        int nc = (t >> 6) + 1;
        if (nc > 31) nc = 31;
        wait_tile_(cnt, tile0 + nc);
      }
      int slot = t & (PD - 1);
      const half8_t* hr = (t & 1) ? (const half8_t*)hb0 : (const half8_t*)hb1;
      _Float16* hw = (t & 1) ? hb1 : hb0;

      float2 xv = xr[slot];
      int ph = t & 3;
      float sv = ph == 0 ? sv_cur.x : ph == 1 ? sv_cur.y
               : ph == 2 ? sv_cur.z : sv_cur.w;
      if (ph == 0) {                 // one float4 surp load per 4 steps
        int tp = t + 4; if (tp > S - 4) tp = S - 4;
        sv_nxt = *(const float4*)(sp + tp);
      }
      {
        int tp = (t + PD < S) ? (t + PD) : (S - 1);
        xr[slot] = ((const float2*)(xp + (size_t)tp * G4))[q];
      }

      float a0 = 0.f, a1 = 0.f, b0 = 0.f, b1 = 0.f;
      #pragma unroll
      for (int j = 0; j < 13; ++j) {
        half8_t hv = hr[j];                        // uniform addr -> broadcast
        half2_t h0 = {hv[0], hv[1]}, h1 = {hv[2], hv[3]};
        half2_t h2 = {hv[4], hv[5]}, h3 = {hv[6], hv[7]};
        a0 = fdot2_(wA[4 * j + 0], h0, a0);
        b0 = fdot2_(wB[4 * j + 0], h0, b0);
        a1 = fdot2_(wA[4 * j + 1], h1, a1);
        b1 = fdot2_(wB[4 * j + 1], h1, b1);
        a0 = fdot2_(wA[4 * j + 2], h2, a0);
        b0 = fdot2_(wB[4 * j + 2], h2, b0);
        a1 = fdot2_(wA[4 * j + 3], h3, a1);
        b1 = fdot2_(wB[4 * j + 3], h3, b1);
      }
      float aA = a0 + a1 + xv.x + sv * wlA;   // even: i_pre ; odd: f_pre
      float aB = b0 + b1 + xv.y + sv * wlB;   // even: g_pre ; odd: o_pre

      float vA = sigmoidf_(aA);                       // i or f
      float sB = sigmoidf_(odd ? aB : 2.0f * aB);
      float vB = odd ? sB : (2.0f * sB - 1.0f);       // o or tanh(g)

      float f_n = __shfl_xor(vA, 1);
      float o_n = __shfl_xor(vB, 1);

      c_reg = f_n * c_reg + vA * vB;                  // c = f*c + i*g
      float tc = 2.0f * sigmoidf_(2.0f * c_reg) - 1.0f;
      float h = o_n * tc;
      if (active && !odd) hw[k] = (_Float16)h;

      if (ph == 3) sv_cur = sv_nxt;
      lds_barrier_();
    }

    // S even -> final h (t = S-1, odd) is in hb1
    if (tid < 3) {
      float acc = cls_b[tid];
      const float* cw = cls_W + tid * (HID + 3);
      #pragma unroll
      for (int j = 0; j < HID; ++j) acc += cw[j] * (float)hb1[j];
      #pragma unroll
      for (int k2 = 0; k2 < 3; ++k2) acc += cw[HID + k2] * sent[b * 3 + k2];
      out[b * 3 + tid] = acc;
    }
  }
}

extern "C" void kernel_launch(void* const* d_in, const int* in_sizes, int n_in,
                              void* d_out, int out_size, void* d_ws, size_t ws_size,
                              hipStream_t stream) {
  const int*   input_ids = (const int*)d_in[0];
  const float* mask      = (const float*)d_in[1];
  const float* sent      = (const float*)d_in[2];
  const float* hs        = (const float*)d_in[3];
  const float* logits    = (const float*)d_in[4];
  const float* W_ih      = (const float*)d_in[5];
  const float* W_hh      = (const float*)d_in[6];
  const float* b_ih      = (const float*)d_in[7];
  const float* b_hh      = (const float*)d_in[8];
  const float* cls_W     = (const float*)d_in[9];
  const float* cls_b     = (const float*)d_in[10];
  float* out = (float*)d_out;

  float* surp  = (float*)d_ws;                       // M_TOT floats
  float* xproj = surp + M_TOT;                       // M_TOT*400 floats
  int*   cnt   = (int*)(xproj + (size_t)M_TOT * G4); // NTM ints

  hipMemsetAsync(cnt, 0, NTM * sizeof(int), stream);
  mega_kernel<<<NBLK, 256, 0, stream>>>(
      logits, input_ids, mask, hs, W_ih, W_hh, b_ih, b_hh,
      sent, cls_W, cls_b, surp, xproj, cnt, out);
}